// Round 7
// baseline (1978.229 us; speedup 1.0000x reference)
//
#include <hip/hip_runtime.h>
#include <cmath>

#define C_DIM 256
#define E_DIM 128
#define S_DIM 4096

typedef __bf16 bf16x8 __attribute__((ext_vector_type(8)));
typedef float  f32x4  __attribute__((ext_vector_type(4)));
typedef short  s16x8  __attribute__((ext_vector_type(8)));
typedef short  s16x4  __attribute__((ext_vector_type(4)));

__device__ __forceinline__ unsigned short f2bf(float f) {
  union { float f; unsigned u; } v; v.f = f;
  unsigned r = v.u + 0x7FFFu + ((v.u >> 16) & 1u);
  return (unsigned short)(r >> 16);
}
__device__ __forceinline__ unsigned short f2bf_tr(float f) {  // truncating
  union { float f; unsigned u; } v; v.f = f;
  return (unsigned short)(v.u >> 16);
}
__device__ __forceinline__ bf16x8 as_bf(s16x8 v) {
  union { s16x8 s; bf16x8 b; } u; u.s = v; return u.b;
}

// ---------------------------------------------------------------------------
// Kernel 0: cast weights fp32 -> bf16. [Wth 32768][Wph 32768][Wproj 65536].
// ---------------------------------------------------------------------------
__global__ __launch_bounds__(256) void cast_w_kernel(
    const float* __restrict__ Wth, const float* __restrict__ Wph,
    const float* __restrict__ Wpr, short* __restrict__ Wb) {
  int t = blockIdx.x * 256 + threadIdx.x;
  int i = t * 4;
  const float* src; int j;
  if (i < 32768)      { src = Wth; j = i; }
  else if (i < 65536) { src = Wph; j = i - 32768; }
  else                { src = Wpr; j = i - 65536; }
  float4 v = *(const float4*)(src + j);
  s16x4 o;
  o[0] = (short)f2bf(v.x); o[1] = (short)f2bf(v.y);
  o[2] = (short)f2bf(v.z); o[3] = (short)f2bf(v.w);
  *(s16x4*)(Wb + i) = o;
}

// ---------------------------------------------------------------------------
// Kernel 1 (MFMA): Q[s,e] = qscale * sum_c Wth[e,c] x[c,s]; K likewise.
// Emits bf16 x. Softmax log2-scale folded into Q. grid 512.
// ---------------------------------------------------------------------------
__global__ __launch_bounds__(256) void mix_kernel(
    const float* __restrict__ x, const short* __restrict__ Wb,
    short* __restrict__ Qg, short* __restrict__ Kg, short* __restrict__ Xb,
    float qscale) {
  __shared__ short lxT[32 * C_DIM];   // [s][c] bf16, swizzled, 16 KB
  int bid = blockIdx.x;
  int n = bid >> 7, s0 = (bid & 127) * 32;
  int tid = threadIdx.x;
  int wid = tid >> 6, lane = tid & 63, l15 = lane & 15, l4 = lane >> 4;

  { // stage x^T tile + emit Xb
    int cp = tid >> 1, su = tid & 1;
    const float* r0 = x + ((size_t)n * C_DIM + 2 * cp) * S_DIM + s0 + su * 16;
    const float* r1 = r0 + S_DIM;
    float a0[16], a1[16];
    #pragma unroll
    for (int j = 0; j < 4; ++j) {
      *(float4*)(a0 + 4 * j) = *(const float4*)(r0 + 4 * j);
      *(float4*)(a1 + 4 * j) = *(const float4*)(r1 + 4 * j);
    }
    short b0[16], b1[16];
    #pragma unroll
    for (int j = 0; j < 16; ++j) { b0[j] = (short)f2bf(a0[j]); b1[j] = (short)f2bf(a1[j]); }
    short* xb0 = Xb + ((size_t)n * C_DIM + 2 * cp) * S_DIM + s0 + su * 16;
    *(s16x8*)(xb0)             = *(s16x8*)(b0);
    *(s16x8*)(xb0 + 8)         = *(s16x8*)(b0 + 8);
    *(s16x8*)(xb0 + S_DIM)     = *(s16x8*)(b1);
    *(s16x8*)(xb0 + S_DIM + 8) = *(s16x8*)(b1 + 8);
    #pragma unroll
    for (int j = 0; j < 16; ++j) {
      int s = su * 16 + j;
      unsigned d = (unsigned)(unsigned short)b0[j] |
                   ((unsigned)(unsigned short)b1[j] << 16);
      *(unsigned*)((char*)lxT + s * 512 + ((4 * cp) ^ ((s & 7) << 4))) = d;
    }
  }
  __syncthreads();

  const short* Wq = Wb;
  const short* Wk = Wb + 32768;
  const f32x4 fzero = {0.f, 0.f, 0.f, 0.f};
  f32x4 accQ[2][2], accK[2][2];
  #pragma unroll
  for (int a = 0; a < 2; ++a)
    #pragma unroll
    for (int b = 0; b < 2; ++b) { accQ[a][b] = fzero; accK[a][b] = fzero; }

  #pragma unroll 2
  for (int kk = 0; kk < 8; ++kk) {
    bf16x8 bfr[2];
    #pragma unroll
    for (int nf = 0; nf < 2; ++nf) {
      int s = nf * 16 + l15;
      bfr[nf] = *(const bf16x8*)((char*)lxT + s * 512 +
                                 ((kk * 64 + l4 * 16) ^ ((s & 7) << 4)));
    }
    #pragma unroll
    for (int mf = 0; mf < 2; ++mf) {
      int e = wid * 32 + mf * 16 + l15;
      bf16x8 aq = *(const bf16x8*)(Wq + e * C_DIM + kk * 32 + l4 * 8);
      bf16x8 ak = *(const bf16x8*)(Wk + e * C_DIM + kk * 32 + l4 * 8);
      #pragma unroll
      for (int nf = 0; nf < 2; ++nf) {
        accQ[mf][nf] = __builtin_amdgcn_mfma_f32_16x16x32_bf16(aq, bfr[nf], accQ[mf][nf], 0, 0, 0);
        accK[mf][nf] = __builtin_amdgcn_mfma_f32_16x16x32_bf16(ak, bfr[nf], accK[mf][nf], 0, 0, 0);
      }
    }
  }

  #pragma unroll
  for (int mf = 0; mf < 2; ++mf) {
    #pragma unroll
    for (int nf = 0; nf < 2; ++nf) {
      int e = wid * 32 + mf * 16 + l4 * 4;
      int s = s0 + nf * 16 + l15;
      s16x4 pq, pk;
      #pragma unroll
      for (int r = 0; r < 4; ++r) {
        pq[r] = (short)f2bf(accQ[mf][nf][r] * qscale);
        pk[r] = (short)f2bf(accK[mf][nf][r]);
      }
      *(s16x4*)(Qg + ((size_t)n * S_DIM + s) * E_DIM + e) = pq;
      *(s16x4*)(Kg + ((size_t)n * S_DIM + s) * E_DIM + e) = pk;
    }
  }
}

// ---------------------------------------------------------------------------
// Kernel 2: flash attention (round-5 structure + 3 isolated fixes):
//   1. 2-deep V prefetch (vpre[2][8]) -> V latency fully hidden.
//   2. double-buffered kpre -> no ds_write/reload register hazard.
//   3. s_setprio(1) around MFMA clusters.
// RAW barriers (lgkmcnt-only). Swapped QK^T. 64-t windows, 65 barriers.
// waves 0-3 QKT+exp+P, waves 4-7 PV + K staging. grid 256, XCD-pinned.
// ---------------------------------------------------------------------------
__global__ __launch_bounds__(512, 2) void attn_kernel(
    const short* __restrict__ Qg, const short* __restrict__ Kg,
    const short* __restrict__ Xb, short* __restrict__ Yg) {
  __shared__ short lK[2 * 64 * E_DIM];   // 32 KB, dbuf, swizzled [t][e]
  __shared__ short lP[2 * 64 * 64];      // 16 KB, dbuf, swizzled [q][t]
  __shared__ float lsred[4 * 64];        // 1 KB

  int bid = blockIdx.x;
  int xcd = bid & 7;            // dispatch round-robins XCDs
  int n   = xcd >> 1;           // batch pinned to an XCD pair
  int s0  = (((xcd & 1) << 5) + (bid >> 3)) * 64;

  int tid = threadIdx.x;
  int wid = tid >> 6, lane = tid & 63;
  int l15 = lane & 15, l4 = lane >> 4;

  const short* Kb = Kg + (size_t)n * S_DIM * E_DIM;
  const short* Vb = Xb + (size_t)n * (size_t)C_DIM * S_DIM;

  const f32x4 fzero = {0.f, 0.f, 0.f, 0.f};

  // ---------------- per-role persistent state ----------------
  bf16x8 qf[4][4];          // QKT waves
  float lsum[4];            // QKT waves: per-(q=l15, t-group l4) partials
  f32x4 acc[4][4];          // PV waves: [qs][ct]
  s16x8 kpre[2][4];         // PV waves: K staging, double-buffered
  s16x8 vpre[2][8];         // PV waves: V tiles, 2-deep prefetch

  int tq = wid;             // QKT: t-quarter
  int cq = wid - 4;         // PV:  c-quarter
  int idx = tid & 255;
  int kr = idx >> 4, kc = idx & 15;   // K staging (PV waves, 256 threads)

  if (wid < 4) {
    #pragma unroll
    for (int qs = 0; qs < 4; ++qs) {
      const short* qp = Qg + ((size_t)n * S_DIM + s0 + qs * 16 + l15) * E_DIM + l4 * 8;
      #pragma unroll
      for (int ec = 0; ec < 4; ++ec) qf[qs][ec] = *(const bf16x8*)(qp + ec * 32);
    }
    #pragma unroll
    for (int j = 0; j < 4; ++j) lsum[j] = 0.f;
  } else {
    #pragma unroll
    for (int a = 0; a < 4; ++a)
      #pragma unroll
      for (int b = 0; b < 4; ++b) acc[a][b] = fzero;
    // stage K tile 0 into buf 0 (transient regs; drained before first barrier)
    s16x8 k0[4];
    #pragma unroll
    for (int j = 0; j < 4; ++j)
      k0[j] = *(const s16x8*)(Kb + (size_t)(kr + 16 * j) * E_DIM + kc * 8);
    #pragma unroll
    for (int j = 0; j < 4; ++j) {
      int r = kr + 16 * j;
      *(s16x8*)((char*)lK + r * 256 + ((kc * 16) ^ ((r & 7) << 4))) = k0[j];
    }
    // prefetch K tile 1 -> kpre[1]; V tile 0 -> vpre[0] (in flight across barrier)
    #pragma unroll
    for (int j = 0; j < 4; ++j)
      kpre[1][j] = *(const s16x8*)(Kb + (size_t)(64 + kr + 16 * j) * E_DIM + kc * 8);
    #pragma unroll
    for (int kk = 0; kk < 2; ++kk)
      #pragma unroll
      for (int ct = 0; ct < 4; ++ct)
        vpre[0][kk * 4 + ct] = *(const s16x8*)(
            Vb + (size_t)(cq * 64 + ct * 16 + l15) * S_DIM + kk * 32 + l4 * 8);
  }
  asm volatile("s_waitcnt lgkmcnt(0)" ::: "memory");
  __builtin_amdgcn_s_barrier();

  // ------------- main: 65 windows, one RAW barrier each -------------
  for (int i = 0; i <= 64; ++i) {
    if (wid < 4) {
      if (i < 64) {
        const char* kb = (const char*)lK + (i & 1) * 16384;
        f32x4 sc[4] = {fzero, fzero, fzero, fzero};
        int trow = tq * 16 + l15;
        int swz = (trow & 7) << 4;
        __builtin_amdgcn_s_setprio(1);
        #pragma unroll
        for (int ec = 0; ec < 4; ++ec) {
          bf16x8 kf = *(const bf16x8*)(kb + trow * 256 + ((ec * 64 + l4 * 16) ^ swz));
          #pragma unroll
          for (int qs = 0; qs < 4; ++qs)   // swapped: D[t][q]
            sc[qs] = __builtin_amdgcn_mfma_f32_16x16x32_bf16(kf, qf[qs][ec], sc[qs], 0, 0, 0);
        }
        __builtin_amdgcn_s_setprio(0);
        char* pw = (char*)lP + (i & 1) * 8192;
        int tb2 = tq * 32 + l4 * 8;     // byte offset of this lane's t-run
        #pragma unroll
        for (int qs = 0; qs < 4; ++qs) {
          float p0 = __builtin_amdgcn_exp2f(sc[qs][0]);
          float p1 = __builtin_amdgcn_exp2f(sc[qs][1]);
          float p2 = __builtin_amdgcn_exp2f(sc[qs][2]);
          float p3 = __builtin_amdgcn_exp2f(sc[qs][3]);
          lsum[qs] += (p0 + p1) + (p2 + p3);
          uint2 dd;
          dd.x = (unsigned)f2bf_tr(p0) | ((unsigned)f2bf_tr(p1) << 16);
          dd.y = (unsigned)f2bf_tr(p2) | ((unsigned)f2bf_tr(p3) << 16);
          int q = qs * 16 + l15;
          *(uint2*)(pw + q * 128 + (tb2 ^ ((q & 7) << 4))) = dd;
        }
      }
    } else {
      // (a) issue V tile i loads (consumed at window i+1) -- 2-deep pipeline
      if (i >= 1 && i <= 63) {
        #pragma unroll
        for (int kk = 0; kk < 2; ++kk)
          #pragma unroll
          for (int ct = 0; ct < 4; ++ct)
            vpre[i & 1][kk * 4 + ct] = *(const s16x8*)(
                Vb + (size_t)(cq * 64 + ct * 16 + l15) * S_DIM + i * 64 + kk * 32 + l4 * 8);
      }
      // (b) commit K tile i+1 from kpre[(i+1)&1] (loaded at window i-1)
      if (i <= 62) {
        char* kw = (char*)lK + ((i + 1) & 1) * 16384;
        #pragma unroll
        for (int j = 0; j < 4; ++j) {
          int r = kr + 16 * j;
          *(s16x8*)(kw + r * 256 + ((kc * 16) ^ ((r & 7) << 4))) = kpre[(i + 1) & 1][j];
        }
      }
      // (c) PV on tile i-1: P from LDS, V from vpre[(i-1)&1] (1+ window old)
      if (i >= 1) {
        const char* pr = (const char*)lP + ((i & 1) ^ 1) * 8192;
        #pragma unroll
        for (int kk = 0; kk < 2; ++kk) {
          bf16x8 pf[4];
          #pragma unroll
          for (int qs = 0; qs < 4; ++qs) {
            int q = qs * 16 + l15;
            pf[qs] = *(const bf16x8*)(pr + q * 128 + ((kk * 64 + l4 * 16) ^ ((q & 7) << 4)));
          }
          __builtin_amdgcn_s_setprio(1);
          #pragma unroll
          for (int ct = 0; ct < 4; ++ct) {
            bf16x8 vf = as_bf(vpre[(i - 1) & 1][kk * 4 + ct]);
            #pragma unroll
            for (int qs = 0; qs < 4; ++qs)
              acc[qs][ct] = __builtin_amdgcn_mfma_f32_16x16x32_bf16(pf[qs], vf, acc[qs][ct], 0, 0, 0);
          }
          __builtin_amdgcn_s_setprio(0);
        }
      }
      // (d) issue K tile i+2 loads into kpre[i&1] (committed at window i+1)
      if (i <= 61) {
        #pragma unroll
        for (int j = 0; j < 4; ++j)
          kpre[i & 1][j] = *(const s16x8*)(Kb + (size_t)((i + 2) * 64 + kr + 16 * j) * E_DIM + kc * 8);
      }
    }
    // RAW barrier: LDS drained, register-destined global loads stay in flight.
    asm volatile("s_waitcnt lgkmcnt(0)" ::: "memory");
    __builtin_amdgcn_s_barrier();
  }

  // ---------------- epilogue ----------------
  if (wid < 4) {
    #pragma unroll
    for (int qs = 0; qs < 4; ++qs) {
      float v = lsum[qs];
      v += __shfl_xor(v, 16);
      v += __shfl_xor(v, 32);
      if (lane < 16) lsred[tq * 64 + qs * 16 + l15] = v;
    }
  }
  __syncthreads();

  short* yst = lK;   // reuse 32 KB as [64 q][256 c] bf16, swizzled
  if (wid >= 4) {
    #pragma unroll
    for (int qs = 0; qs < 4; ++qs) {
      #pragma unroll
      for (int r = 0; r < 4; ++r) {
        int q = qs * 16 + l4 * 4 + r;
        float tot = lsred[q] + lsred[64 + q] + lsred[128 + q] + lsred[192 + q];
        float rl = 1.0f / tot;
        #pragma unroll
        for (int ct = 0; ct < 4; ++ct) {
          int c = cq * 64 + ct * 16 + l15;
          *(unsigned short*)((char*)yst + q * 512 + ((c * 2) ^ ((q & 7) << 4))) =
              f2bf_tr(acc[qs][ct][r] * rl);
        }
      }
    }
  }
  __syncthreads();

  int rr = tid >> 3, chb = tid & 7;
  #pragma unroll
  for (int it = 0; it < 4; ++it) {
    int ch = chb + 8 * it;
    s16x8 v = *(const s16x8*)((char*)yst + rr * 512 + ((ch * 16) ^ ((rr & 7) << 4)));
    *(s16x8*)(Yg + ((size_t)n * S_DIM + s0 + rr) * C_DIM + ch * 8) = v;
  }
}

// ---------------------------------------------------------------------------
// Kernel 3 (MFMA, zero LDS): out[o,s] = x[o,s] + sum_c Wp[o,c] y[s,c]
// ---------------------------------------------------------------------------
__global__ __launch_bounds__(256) void proj_kernel(
    const short* __restrict__ Yg, const short* __restrict__ Wpb,
    const float* __restrict__ x, float* __restrict__ out) {
  int bid = blockIdx.x;
  int n = bid >> 7, s0 = (bid & 127) * 32;
  int tid = threadIdx.x;
  int wid = tid >> 6, lane = tid & 63, l15 = lane & 15, l4 = lane >> 4;

  const f32x4 fzero = {0.f, 0.f, 0.f, 0.f};
  f32x4 acc[2][4];
  #pragma unroll
  for (int a = 0; a < 2; ++a)
    #pragma unroll
    for (int b = 0; b < 4; ++b) acc[a][b] = fzero;

  const short* ybase = Yg + (size_t)n * S_DIM * C_DIM;

  #pragma unroll 2
  for (int kk = 0; kk < 8; ++kk) {
    bf16x8 af[2];
    #pragma unroll
    for (int mf = 0; mf < 2; ++mf)
      af[mf] = *(const bf16x8*)(ybase + (size_t)(s0 + mf * 16 + l15) * C_DIM +
                                kk * 32 + l4 * 8);
    #pragma unroll
    for (int nf = 0; nf < 4; ++nf) {
      int o = wid * 64 + nf * 16 + l15;
      bf16x8 bfr = *(const bf16x8*)(Wpb + o * C_DIM + kk * 32 + l4 * 8);
      #pragma unroll
      for (int mf = 0; mf < 2; ++mf)
        acc[mf][nf] = __builtin_amdgcn_mfma_f32_16x16x32_bf16(af[mf], bfr, acc[mf][nf], 0, 0, 0);
    }
  }

  #pragma unroll
  for (int mf = 0; mf < 2; ++mf) {
    #pragma unroll
    for (int nf = 0; nf < 4; ++nf) {
      int o = wid * 64 + nf * 16 + l15;
      size_t idx = ((size_t)n * C_DIM + o) * (size_t)S_DIM + s0 + mf * 16 + l4 * 4;
      float4 xv = *(const float4*)(x + idx);
      float4 r;
      r.x = xv.x + acc[mf][nf][0];
      r.y = xv.y + acc[mf][nf][1];
      r.z = xv.z + acc[mf][nf][2];
      r.w = xv.w + acc[mf][nf][3];
      *(float4*)(out + idx) = r;
    }
  }
}

// ---------------------------------------------------------------------------
extern "C" void kernel_launch(void* const* d_in, const int* in_sizes, int n_in,
                              void* d_out, int out_size, void* d_ws, size_t ws_size,
                              hipStream_t stream) {
  const float* x   = (const float*)d_in[0];
  const float* Wth = (const float*)d_in[1];
  const float* Wph = (const float*)d_in[2];
  const float* Wpr = (const float*)d_in[3];
  float* out = (float*)d_out;

  short* q_ws  = (short*)d_ws;                              // 4 MB  [N,S,E]
  short* k_ws  = q_ws  + (size_t)4 * S_DIM * E_DIM;         // 4 MB  [N,S,E]
  short* xb_ws = k_ws  + (size_t)4 * S_DIM * E_DIM;         // 8 MB  [N,C,S]
  short* y_ws  = xb_ws + (size_t)4 * C_DIM * S_DIM;         // 8 MB  [N,S,C]
  short* wb_ws = y_ws  + (size_t)4 * S_DIM * C_DIM;         // 256 KB bf16 weights

  float qscale = 1.4426950408889634f / sqrtf(128.0f);       // log2(e)/sqrt(E)

  cast_w_kernel<<<128, 256, 0, stream>>>(Wth, Wph, Wpr, wb_ws);
  mix_kernel<<<512, 256, 0, stream>>>(x, wb_ws, q_ws, k_ws, xb_ws, qscale);
  attn_kernel<<<256, 512, 0, stream>>>(q_ws, k_ws, xb_ws, y_ws);
  proj_kernel<<<512, 256, 0, stream>>>(y_ws, wb_ws + 65536, x, out);
}

// Round 8
// 207.148 us; speedup vs baseline: 9.5498x; 9.5498x over previous
//
#include <hip/hip_runtime.h>
#include <cmath>

#define C_DIM 256
#define E_DIM 128
#define S_DIM 4096

typedef __bf16 bf16x8 __attribute__((ext_vector_type(8)));
typedef float  f32x4  __attribute__((ext_vector_type(4)));
typedef short  s16x8  __attribute__((ext_vector_type(8)));
typedef short  s16x4  __attribute__((ext_vector_type(4)));

__device__ __forceinline__ unsigned short f2bf(float f) {
  union { float f; unsigned u; } v; v.f = f;
  unsigned r = v.u + 0x7FFFu + ((v.u >> 16) & 1u);
  return (unsigned short)(r >> 16);
}
__device__ __forceinline__ unsigned short f2bf_tr(float f) {  // truncating
  union { float f; unsigned u; } v; v.f = f;
  return (unsigned short)(v.u >> 16);
}
__device__ __forceinline__ bf16x8 as_bf(s16x8 v) {
  union { s16x8 s; bf16x8 b; } u; u.s = v; return u.b;
}

// ---------------------------------------------------------------------------
// Kernel 0: cast weights fp32 -> bf16. [Wth 32768][Wph 32768][Wproj 65536].
// ---------------------------------------------------------------------------
__global__ __launch_bounds__(256) void cast_w_kernel(
    const float* __restrict__ Wth, const float* __restrict__ Wph,
    const float* __restrict__ Wpr, short* __restrict__ Wb) {
  int t = blockIdx.x * 256 + threadIdx.x;
  int i = t * 4;
  const float* src; int j;
  if (i < 32768)      { src = Wth; j = i; }
  else if (i < 65536) { src = Wph; j = i - 32768; }
  else                { src = Wpr; j = i - 65536; }
  float4 v = *(const float4*)(src + j);
  s16x4 o;
  o[0] = (short)f2bf(v.x); o[1] = (short)f2bf(v.y);
  o[2] = (short)f2bf(v.z); o[3] = (short)f2bf(v.w);
  *(s16x4*)(Wb + i) = o;
}

// ---------------------------------------------------------------------------
// Kernel 1 (MFMA): Q[s,e] = qscale * sum_c Wth[e,c] x[c,s]; K likewise.
// Emits bf16 x. Softmax log2-scale folded into Q. grid 512.
// ---------------------------------------------------------------------------
__global__ __launch_bounds__(256) void mix_kernel(
    const float* __restrict__ x, const short* __restrict__ Wb,
    short* __restrict__ Qg, short* __restrict__ Kg, short* __restrict__ Xb,
    float qscale) {
  __shared__ short lxT[32 * C_DIM];   // [s][c] bf16, swizzled, 16 KB
  int bid = blockIdx.x;
  int n = bid >> 7, s0 = (bid & 127) * 32;
  int tid = threadIdx.x;
  int wid = tid >> 6, lane = tid & 63, l15 = lane & 15, l4 = lane >> 4;

  { // stage x^T tile + emit Xb
    int cp = tid >> 1, su = tid & 1;
    const float* r0 = x + ((size_t)n * C_DIM + 2 * cp) * S_DIM + s0 + su * 16;
    const float* r1 = r0 + S_DIM;
    float a0[16], a1[16];
    #pragma unroll
    for (int j = 0; j < 4; ++j) {
      *(float4*)(a0 + 4 * j) = *(const float4*)(r0 + 4 * j);
      *(float4*)(a1 + 4 * j) = *(const float4*)(r1 + 4 * j);
    }
    short b0[16], b1[16];
    #pragma unroll
    for (int j = 0; j < 16; ++j) { b0[j] = (short)f2bf(a0[j]); b1[j] = (short)f2bf(a1[j]); }
    short* xb0 = Xb + ((size_t)n * C_DIM + 2 * cp) * S_DIM + s0 + su * 16;
    *(s16x8*)(xb0)             = *(s16x8*)(b0);
    *(s16x8*)(xb0 + 8)         = *(s16x8*)(b0 + 8);
    *(s16x8*)(xb0 + S_DIM)     = *(s16x8*)(b1);
    *(s16x8*)(xb0 + S_DIM + 8) = *(s16x8*)(b1 + 8);
    #pragma unroll
    for (int j = 0; j < 16; ++j) {
      int s = su * 16 + j;
      unsigned d = (unsigned)(unsigned short)b0[j] |
                   ((unsigned)(unsigned short)b1[j] << 16);
      *(unsigned*)((char*)lxT + s * 512 + ((4 * cp) ^ ((s & 7) << 4))) = d;
    }
  }
  __syncthreads();

  const short* Wq = Wb;
  const short* Wk = Wb + 32768;
  const f32x4 fzero = {0.f, 0.f, 0.f, 0.f};
  f32x4 accQ[2][2], accK[2][2];
  #pragma unroll
  for (int a = 0; a < 2; ++a)
    #pragma unroll
    for (int b = 0; b < 2; ++b) { accQ[a][b] = fzero; accK[a][b] = fzero; }

  #pragma unroll 2
  for (int kk = 0; kk < 8; ++kk) {
    bf16x8 bfr[2];
    #pragma unroll
    for (int nf = 0; nf < 2; ++nf) {
      int s = nf * 16 + l15;
      bfr[nf] = *(const bf16x8*)((char*)lxT + s * 512 +
                                 ((kk * 64 + l4 * 16) ^ ((s & 7) << 4)));
    }
    #pragma unroll
    for (int mf = 0; mf < 2; ++mf) {
      int e = wid * 32 + mf * 16 + l15;
      bf16x8 aq = *(const bf16x8*)(Wq + e * C_DIM + kk * 32 + l4 * 8);
      bf16x8 ak = *(const bf16x8*)(Wk + e * C_DIM + kk * 32 + l4 * 8);
      #pragma unroll
      for (int nf = 0; nf < 2; ++nf) {
        accQ[mf][nf] = __builtin_amdgcn_mfma_f32_16x16x32_bf16(aq, bfr[nf], accQ[mf][nf], 0, 0, 0);
        accK[mf][nf] = __builtin_amdgcn_mfma_f32_16x16x32_bf16(ak, bfr[nf], accK[mf][nf], 0, 0, 0);
      }
    }
  }

  #pragma unroll
  for (int mf = 0; mf < 2; ++mf) {
    #pragma unroll
    for (int nf = 0; nf < 2; ++nf) {
      int e = wid * 32 + mf * 16 + l4 * 4;
      int s = s0 + nf * 16 + l15;
      s16x4 pq, pk;
      #pragma unroll
      for (int r = 0; r < 4; ++r) {
        pq[r] = (short)f2bf(accQ[mf][nf][r] * qscale);
        pk[r] = (short)f2bf(accK[mf][nf][r]);
      }
      *(s16x4*)(Qg + ((size_t)n * S_DIM + s) * E_DIM + e) = pq;
      *(s16x4*)(Kg + ((size_t)n * S_DIM + s) * E_DIM + e) = pk;
    }
  }
}

// ---------------------------------------------------------------------------
// Kernel 2: flash attention. Round-7 SCHEDULE with STATIC register indexing
// (rule #20 fix): main loop unrolled 2 windows/iter, double buffers are
// NAMED register sets (vpreE/vpreO, kpreE/kpreO) -> all indices compile-time.
// RAW lgkmcnt-only barriers; swapped QK^T; setprio around MFMA clusters.
// waves 0-3 QKT+exp+P, waves 4-7 PV + K staging. grid 256, XCD-pinned.
// ---------------------------------------------------------------------------

#define QKT_BODY(KBUF)                                                        \
  {                                                                           \
    const char* kb = (const char*)lK + (KBUF) * 16384;                        \
    char* pw = (char*)lP + (KBUF) * 8192;                                     \
    f32x4 sc[4] = {fzero, fzero, fzero, fzero};                               \
    int trow = tq * 16 + l15;                                                 \
    int swz = (trow & 7) << 4;                                                \
    __builtin_amdgcn_s_setprio(1);                                            \
    _Pragma("unroll")                                                         \
    for (int ec = 0; ec < 4; ++ec) {                                          \
      bf16x8 kf = *(const bf16x8*)(kb + trow * 256 + ((ec * 64 + l4 * 16) ^ swz)); \
      _Pragma("unroll")                                                       \
      for (int qs = 0; qs < 4; ++qs)                                          \
        sc[qs] = __builtin_amdgcn_mfma_f32_16x16x32_bf16(kf, qf[qs][ec], sc[qs], 0, 0, 0); \
    }                                                                         \
    __builtin_amdgcn_s_setprio(0);                                            \
    int tb2 = tq * 32 + l4 * 8;                                               \
    _Pragma("unroll")                                                         \
    for (int qs = 0; qs < 4; ++qs) {                                          \
      float p0 = __builtin_amdgcn_exp2f(sc[qs][0]);                           \
      float p1 = __builtin_amdgcn_exp2f(sc[qs][1]);                           \
      float p2 = __builtin_amdgcn_exp2f(sc[qs][2]);                           \
      float p3 = __builtin_amdgcn_exp2f(sc[qs][3]);                           \
      lsum[qs] += (p0 + p1) + (p2 + p3);                                      \
      uint2 dd;                                                               \
      dd.x = (unsigned)f2bf_tr(p0) | ((unsigned)f2bf_tr(p1) << 16);           \
      dd.y = (unsigned)f2bf_tr(p2) | ((unsigned)f2bf_tr(p3) << 16);           \
      int q = qs * 16 + l15;                                                  \
      *(uint2*)(pw + q * 128 + (tb2 ^ ((q & 7) << 4))) = dd;                  \
    }                                                                         \
  }

#define PV_VISSUE(vdst, TI)                                                   \
  _Pragma("unroll")                                                           \
  for (int kk = 0; kk < 2; ++kk)                                              \
    _Pragma("unroll")                                                         \
    for (int ct = 0; ct < 4; ++ct)                                            \
      vdst[kk * 4 + ct] = *(const s16x8*)(                                    \
          Vb + (size_t)(cq * 64 + ct * 16 + l15) * S_DIM + (TI) * 64 + kk * 32 + l4 * 8);

#define PV_KCOMMIT(ksrc, KBUFW)                                               \
  {                                                                           \
    char* kw = (char*)lK + (KBUFW) * 16384;                                   \
    _Pragma("unroll")                                                         \
    for (int jj = 0; jj < 4; ++jj) {                                          \
      int r = kr + 16 * jj;                                                   \
      *(s16x8*)(kw + r * 256 + ((kc * 16) ^ ((r & 7) << 4))) = ksrc[jj];      \
    }                                                                         \
  }

#define PV_KLOAD(kdst, TI)                                                    \
  _Pragma("unroll")                                                           \
  for (int jj = 0; jj < 4; ++jj)                                              \
    kdst[jj] = *(const s16x8*)(Kb + (size_t)((TI) * 64 + kr + 16 * jj) * E_DIM + kc * 8);

#define PV_MFMA(vsrc, PBUF)                                                   \
  {                                                                           \
    const char* pr = (const char*)lP + (PBUF) * 8192;                         \
    _Pragma("unroll")                                                         \
    for (int kk = 0; kk < 2; ++kk) {                                          \
      bf16x8 pf[4];                                                           \
      _Pragma("unroll")                                                       \
      for (int qs = 0; qs < 4; ++qs) {                                        \
        int q = qs * 16 + l15;                                                \
        pf[qs] = *(const bf16x8*)(pr + q * 128 + ((kk * 64 + l4 * 16) ^ ((q & 7) << 4))); \
      }                                                                       \
      __builtin_amdgcn_s_setprio(1);                                          \
      _Pragma("unroll")                                                       \
      for (int ct = 0; ct < 4; ++ct) {                                        \
        bf16x8 vf = as_bf(vsrc[kk * 4 + ct]);                                 \
        _Pragma("unroll")                                                     \
        for (int qs = 0; qs < 4; ++qs)                                        \
          acc[qs][ct] = __builtin_amdgcn_mfma_f32_16x16x32_bf16(pf[qs], vf, acc[qs][ct], 0, 0, 0); \
      }                                                                       \
      __builtin_amdgcn_s_setprio(0);                                          \
    }                                                                         \
  }

#define RAW_BARRIER()                                                         \
  asm volatile("s_waitcnt lgkmcnt(0)" ::: "memory");                          \
  __builtin_amdgcn_s_barrier();

__global__ __launch_bounds__(512, 2) void attn_kernel(
    const short* __restrict__ Qg, const short* __restrict__ Kg,
    const short* __restrict__ Xb, short* __restrict__ Yg) {
  __shared__ short lK[2 * 64 * E_DIM];   // 32 KB, dbuf, swizzled [t][e]
  __shared__ short lP[2 * 64 * 64];      // 16 KB, dbuf, swizzled [q][t]
  __shared__ float lsred[4 * 64];        // 1 KB

  int bid = blockIdx.x;
  int xcd = bid & 7;            // dispatch round-robins XCDs
  int n   = xcd >> 1;           // batch pinned to an XCD pair
  int s0  = (((xcd & 1) << 5) + (bid >> 3)) * 64;

  int tid = threadIdx.x;
  int wid = tid >> 6, lane = tid & 63;
  int l15 = lane & 15, l4 = lane >> 4;

  const short* Kb = Kg + (size_t)n * S_DIM * E_DIM;
  const short* Vb = Xb + (size_t)n * (size_t)C_DIM * S_DIM;

  const f32x4 fzero = {0.f, 0.f, 0.f, 0.f};

  // ---------------- per-role persistent state (ALL statically indexed) ----
  bf16x8 qf[4][4];          // QKT waves
  float lsum[4];            // QKT waves
  f32x4 acc[4][4];          // PV waves
  s16x8 kpreE[4], kpreO[4]; // PV waves: K staging, even/odd tile parity
  s16x8 vpreE[8], vpreO[8]; // PV waves: V tiles,   even/odd tile parity

  int tq = wid;             // QKT: t-quarter
  int cq = wid - 4;         // PV:  c-quarter
  int idx = tid & 255;
  int kr = idx >> 4, kc = idx & 15;   // K staging (PV waves, 256 threads)

  if (wid < 4) {
    #pragma unroll
    for (int qs = 0; qs < 4; ++qs) {
      const short* qp = Qg + ((size_t)n * S_DIM + s0 + qs * 16 + l15) * E_DIM + l4 * 8;
      #pragma unroll
      for (int ec = 0; ec < 4; ++ec) qf[qs][ec] = *(const bf16x8*)(qp + ec * 32);
    }
    #pragma unroll
    for (int j = 0; j < 4; ++j) lsum[j] = 0.f;
  } else {
    #pragma unroll
    for (int a = 0; a < 4; ++a)
      #pragma unroll
      for (int b = 0; b < 4; ++b) acc[a][b] = fzero;
    // stage K tile 0 into lK buf0 (transient regs, waited by the ds_write)
    s16x8 k0[4];
    #pragma unroll
    for (int j = 0; j < 4; ++j)
      k0[j] = *(const s16x8*)(Kb + (size_t)(kr + 16 * j) * E_DIM + kc * 8);
    #pragma unroll
    for (int j = 0; j < 4; ++j) {
      int r = kr + 16 * j;
      *(s16x8*)((char*)lK + r * 256 + ((kc * 16) ^ ((r & 7) << 4))) = k0[j];
    }
    // prefetch K tile 1 -> kpreO; V tile 0 -> vpreE (in flight across barrier)
    PV_KLOAD(kpreO, 1);
    PV_VISSUE(vpreE, 0);
  }
  RAW_BARRIER();

  // ------------- main: 32 iterations x 2 windows, static buffers -----------
  for (int j = 0; j < 32; ++j) {
    int i0 = 2 * j;
    // ---- window i0 (even): QKT on lK buf0 -> lP buf0
    if (wid < 4) {
      QKT_BODY(0);
    } else {
      if (j > 0)  PV_VISSUE(vpreE, i0);       // V tile i0 (cons. at i0+1)
      PV_KCOMMIT(kpreO, 1);                    // K tile i0+1 -> buf1
      if (j > 0)  PV_MFMA(vpreO, 1);           // PV tile i0-1 (odd), P buf1
      if (j < 31) PV_KLOAD(kpreE, i0 + 2);     // K tile i0+2
    }
    RAW_BARRIER();
    // ---- window i0+1 (odd): QKT on lK buf1 -> lP buf1
    if (wid < 4) {
      QKT_BODY(1);
    } else {
      PV_VISSUE(vpreO, i0 + 1);                // V tile i0+1 (cons. at i0+2)
      if (j < 31) PV_KCOMMIT(kpreE, 0);        // K tile i0+2 -> buf0
      PV_MFMA(vpreE, 0);                       // PV tile i0 (even), P buf0
      if (j < 31) PV_KLOAD(kpreO, i0 + 3);     // K tile i0+3
    }
    RAW_BARRIER();
  }
  // final window 64: PV on tile 63 (P in buf1, V in vpreO)
  if (wid >= 4) {
    PV_MFMA(vpreO, 1);
  }

  // ---------------- epilogue ----------------
  if (wid < 4) {
    #pragma unroll
    for (int qs = 0; qs < 4; ++qs) {
      float v = lsum[qs];
      v += __shfl_xor(v, 16);
      v += __shfl_xor(v, 32);
      if (lane < 16) lsred[tq * 64 + qs * 16 + l15] = v;
    }
  }
  __syncthreads();

  short* yst = lK;   // reuse 32 KB as [64 q][256 c] bf16, swizzled
  if (wid >= 4) {
    #pragma unroll
    for (int qs = 0; qs < 4; ++qs) {
      #pragma unroll
      for (int r = 0; r < 4; ++r) {
        int q = qs * 16 + l4 * 4 + r;
        float tot = lsred[q] + lsred[64 + q] + lsred[128 + q] + lsred[192 + q];
        float rl = 1.0f / tot;
        #pragma unroll
        for (int ct = 0; ct < 4; ++ct) {
          int c = cq * 64 + ct * 16 + l15;
          *(unsigned short*)((char*)yst + q * 512 + ((c * 2) ^ ((q & 7) << 4))) =
              f2bf_tr(acc[qs][ct][r] * rl);
        }
      }
    }
  }
  __syncthreads();

  int rr = tid >> 3, chb = tid & 7;
  #pragma unroll
  for (int it = 0; it < 4; ++it) {
    int ch = chb + 8 * it;
    s16x8 v = *(const s16x8*)((char*)yst + rr * 512 + ((ch * 16) ^ ((rr & 7) << 4)));
    *(s16x8*)(Yg + ((size_t)n * S_DIM + s0 + rr) * C_DIM + ch * 8) = v;
  }
}

// ---------------------------------------------------------------------------
// Kernel 3 (MFMA, zero LDS): out[o,s] = x[o,s] + sum_c Wp[o,c] y[s,c]
// ---------------------------------------------------------------------------
__global__ __launch_bounds__(256) void proj_kernel(
    const short* __restrict__ Yg, const short* __restrict__ Wpb,
    const float* __restrict__ x, float* __restrict__ out) {
  int bid = blockIdx.x;
  int n = bid >> 7, s0 = (bid & 127) * 32;
  int tid = threadIdx.x;
  int wid = tid >> 6, lane = tid & 63, l15 = lane & 15, l4 = lane >> 4;

  const f32x4 fzero = {0.f, 0.f, 0.f, 0.f};
  f32x4 acc[2][4];
  #pragma unroll
  for (int a = 0; a < 2; ++a)
    #pragma unroll
    for (int b = 0; b < 4; ++b) acc[a][b] = fzero;

  const short* ybase = Yg + (size_t)n * S_DIM * C_DIM;

  #pragma unroll 2
  for (int kk = 0; kk < 8; ++kk) {
    bf16x8 af[2];
    #pragma unroll
    for (int mf = 0; mf < 2; ++mf)
      af[mf] = *(const bf16x8*)(ybase + (size_t)(s0 + mf * 16 + l15) * C_DIM +
                                kk * 32 + l4 * 8);
    #pragma unroll
    for (int nf = 0; nf < 4; ++nf) {
      int o = wid * 64 + nf * 16 + l15;
      bf16x8 bfr = *(const bf16x8*)(Wpb + o * C_DIM + kk * 32 + l4 * 8);
      #pragma unroll
      for (int mf = 0; mf < 2; ++mf)
        acc[mf][nf] = __builtin_amdgcn_mfma_f32_16x16x32_bf16(af[mf], bfr, acc[mf][nf], 0, 0, 0);
    }
  }

  #pragma unroll
  for (int mf = 0; mf < 2; ++mf) {
    #pragma unroll
    for (int nf = 0; nf < 4; ++nf) {
      int o = wid * 64 + nf * 16 + l15;
      size_t idx = ((size_t)n * C_DIM + o) * (size_t)S_DIM + s0 + mf * 16 + l4 * 4;
      float4 xv = *(const float4*)(x + idx);
      float4 r;
      r.x = xv.x + acc[mf][nf][0];
      r.y = xv.y + acc[mf][nf][1];
      r.z = xv.z + acc[mf][nf][2];
      r.w = xv.w + acc[mf][nf][3];
      *(float4*)(out + idx) = r;
    }
  }
}

// ---------------------------------------------------------------------------
extern "C" void kernel_launch(void* const* d_in, const int* in_sizes, int n_in,
                              void* d_out, int out_size, void* d_ws, size_t ws_size,
                              hipStream_t stream) {
  const float* x   = (const float*)d_in[0];
  const float* Wth = (const float*)d_in[1];
  const float* Wph = (const float*)d_in[2];
  const float* Wpr = (const float*)d_in[3];
  float* out = (float*)d_out;

  short* q_ws  = (short*)d_ws;                              // 4 MB  [N,S,E]
  short* k_ws  = q_ws  + (size_t)4 * S_DIM * E_DIM;         // 4 MB  [N,S,E]
  short* xb_ws = k_ws  + (size_t)4 * S_DIM * E_DIM;         // 8 MB  [N,C,S]
  short* y_ws  = xb_ws + (size_t)4 * C_DIM * S_DIM;         // 8 MB  [N,S,C]
  short* wb_ws = y_ws  + (size_t)4 * S_DIM * C_DIM;         // 256 KB bf16 weights

  float qscale = 1.4426950408889634f / sqrtf(128.0f);       // log2(e)/sqrt(E)

  cast_w_kernel<<<128, 256, 0, stream>>>(Wth, Wph, Wpr, wb_ws);
  mix_kernel<<<512, 256, 0, stream>>>(x, wb_ws, q_ws, k_ws, xb_ws, qscale);
  attn_kernel<<<256, 512, 0, stream>>>(q_ws, k_ws, xb_ws, y_ws);
  proj_kernel<<<512, 256, 0, stream>>>(y_ws, wb_ws + 65536, x, out);
}

// Round 9
// 115.626 us; speedup vs baseline: 17.1088x; 1.7915x over previous
//
#include <hip/hip_runtime.h>
#include <cmath>

#define C_DIM 256
#define E_DIM 128
#define S_DIM 4096

typedef __bf16 bf16x8 __attribute__((ext_vector_type(8)));
typedef float  f32x4  __attribute__((ext_vector_type(4)));
typedef short  s16x8  __attribute__((ext_vector_type(8)));
typedef short  s16x4  __attribute__((ext_vector_type(4)));

__device__ __forceinline__ unsigned short f2bf(float f) {
  union { float f; unsigned u; } v; v.f = f;
  unsigned r = v.u + 0x7FFFu + ((v.u >> 16) & 1u);
  return (unsigned short)(r >> 16);
}
__device__ __forceinline__ unsigned short f2bf_tr(float f) {  // truncating
  union { float f; unsigned u; } v; v.f = f;
  return (unsigned short)(v.u >> 16);
}
__device__ __forceinline__ bf16x8 as_bf(s16x8 v) {
  union { s16x8 s; bf16x8 b; } u; u.s = v; return u.b;
}
// 16B register-union bitcasts (compile to nothing)
__device__ __forceinline__ bf16x8 f2b8(f32x4 v) { union { f32x4 f; bf16x8 b; } u; u.f = v; return u.b; }
__device__ __forceinline__ f32x4 b2f8(bf16x8 v) { union { bf16x8 b; f32x4 f; } u; u.b = v; return u.f; }
__device__ __forceinline__ f32x4 s2f8(s16x8 v)  { union { s16x8 s; f32x4 f; } u; u.s = v; return u.f; }
__device__ __forceinline__ s16x8 f2s8(f32x4 v)  { union { f32x4 f; s16x8 s; } u; u.f = v; return u.s; }

// ---------------------------------------------------------------------------
// Kernel 0: cast weights fp32 -> bf16. [Wth 32768][Wph 32768][Wproj 65536].
// ---------------------------------------------------------------------------
__global__ __launch_bounds__(256) void cast_w_kernel(
    const float* __restrict__ Wth, const float* __restrict__ Wph,
    const float* __restrict__ Wpr, short* __restrict__ Wb) {
  int t = blockIdx.x * 256 + threadIdx.x;
  int i = t * 4;
  const float* src; int j;
  if (i < 32768)      { src = Wth; j = i; }
  else if (i < 65536) { src = Wph; j = i - 32768; }
  else                { src = Wpr; j = i - 65536; }
  float4 v = *(const float4*)(src + j);
  s16x4 o;
  o[0] = (short)f2bf(v.x); o[1] = (short)f2bf(v.y);
  o[2] = (short)f2bf(v.z); o[3] = (short)f2bf(v.w);
  *(s16x4*)(Wb + i) = o;
}

// ---------------------------------------------------------------------------
// Kernel 1 (MFMA): Q[s,e] = qscale * sum_c Wth[e,c] x[c,s]; K likewise.
// Emits bf16 x. Softmax log2-scale folded into Q. grid 512.
// ---------------------------------------------------------------------------
__global__ __launch_bounds__(256) void mix_kernel(
    const float* __restrict__ x, const short* __restrict__ Wb,
    short* __restrict__ Qg, short* __restrict__ Kg, short* __restrict__ Xb,
    float qscale) {
  __shared__ short lxT[32 * C_DIM];   // [s][c] bf16, swizzled, 16 KB
  int bid = blockIdx.x;
  int n = bid >> 7, s0 = (bid & 127) * 32;
  int tid = threadIdx.x;
  int wid = tid >> 6, lane = tid & 63, l15 = lane & 15, l4 = lane >> 4;

  { // stage x^T tile + emit Xb
    int cp = tid >> 1, su = tid & 1;
    const float* r0 = x + ((size_t)n * C_DIM + 2 * cp) * S_DIM + s0 + su * 16;
    const float* r1 = r0 + S_DIM;
    float a0[16], a1[16];
    #pragma unroll
    for (int j = 0; j < 4; ++j) {
      *(float4*)(a0 + 4 * j) = *(const float4*)(r0 + 4 * j);
      *(float4*)(a1 + 4 * j) = *(const float4*)(r1 + 4 * j);
    }
    short b0[16], b1[16];
    #pragma unroll
    for (int j = 0; j < 16; ++j) { b0[j] = (short)f2bf(a0[j]); b1[j] = (short)f2bf(a1[j]); }
    short* xb0 = Xb + ((size_t)n * C_DIM + 2 * cp) * S_DIM + s0 + su * 16;
    *(s16x8*)(xb0)             = *(s16x8*)(b0);
    *(s16x8*)(xb0 + 8)         = *(s16x8*)(b0 + 8);
    *(s16x8*)(xb0 + S_DIM)     = *(s16x8*)(b1);
    *(s16x8*)(xb0 + S_DIM + 8) = *(s16x8*)(b1 + 8);
    #pragma unroll
    for (int j = 0; j < 16; ++j) {
      int s = su * 16 + j;
      unsigned d = (unsigned)(unsigned short)b0[j] |
                   ((unsigned)(unsigned short)b1[j] << 16);
      *(unsigned*)((char*)lxT + s * 512 + ((4 * cp) ^ ((s & 7) << 4))) = d;
    }
  }
  __syncthreads();

  const short* Wq = Wb;
  const short* Wk = Wb + 32768;
  const f32x4 fzero = {0.f, 0.f, 0.f, 0.f};
  f32x4 accQ[2][2], accK[2][2];
  #pragma unroll
  for (int a = 0; a < 2; ++a)
    #pragma unroll
    for (int b = 0; b < 2; ++b) { accQ[a][b] = fzero; accK[a][b] = fzero; }

  #pragma unroll 2
  for (int kk = 0; kk < 8; ++kk) {
    bf16x8 bfr[2];
    #pragma unroll
    for (int nf = 0; nf < 2; ++nf) {
      int s = nf * 16 + l15;
      bfr[nf] = *(const bf16x8*)((char*)lxT + s * 512 +
                                 ((kk * 64 + l4 * 16) ^ ((s & 7) << 4)));
    }
    #pragma unroll
    for (int mf = 0; mf < 2; ++mf) {
      int e = wid * 32 + mf * 16 + l15;
      bf16x8 aq = *(const bf16x8*)(Wq + e * C_DIM + kk * 32 + l4 * 8);
      bf16x8 ak = *(const bf16x8*)(Wk + e * C_DIM + kk * 32 + l4 * 8);
      #pragma unroll
      for (int nf = 0; nf < 2; ++nf) {
        accQ[mf][nf] = __builtin_amdgcn_mfma_f32_16x16x32_bf16(aq, bfr[nf], accQ[mf][nf], 0, 0, 0);
        accK[mf][nf] = __builtin_amdgcn_mfma_f32_16x16x32_bf16(ak, bfr[nf], accK[mf][nf], 0, 0, 0);
      }
    }
  }

  #pragma unroll
  for (int mf = 0; mf < 2; ++mf) {
    #pragma unroll
    for (int nf = 0; nf < 2; ++nf) {
      int e = wid * 32 + mf * 16 + l4 * 4;
      int s = s0 + nf * 16 + l15;
      s16x4 pq, pk;
      #pragma unroll
      for (int r = 0; r < 4; ++r) {
        pq[r] = (short)f2bf(accQ[mf][nf][r] * qscale);
        pk[r] = (short)f2bf(accK[mf][nf][r]);
      }
      *(s16x4*)(Qg + ((size_t)n * S_DIM + s) * E_DIM + e) = pq;
      *(s16x4*)(Kg + ((size_t)n * S_DIM + s) * E_DIM + e) = pk;
    }
  }
}

// ---------------------------------------------------------------------------
// Kernel 2: flash attention. Round-8 schedule + ROLE-UNIONED registers:
//   RA[16] (64 reg) = QKT qf[qs][ec]      | PV vpreE (RA[0..7]) / vpreO (RA[8..15])
//   RB[8]  (32 reg) = QKT sc[qs] (RB[0..3]) | PV kpreE (RB[0..3]) / kpreO (RB[4..7])
// acc[4][4] -> AGPRs. All indices compile-time (2-window unroll).
// RAW lgkmcnt-only barriers; swapped QK^T; setprio around MFMA clusters.
// waves 0-3 QKT+exp+P, waves 4-7 PV + K staging. grid 256, XCD-pinned.
// ---------------------------------------------------------------------------

#define QF(qs, ec) f2b8(RA[(qs) * 4 + (ec)])

#define QKT_BODY(KBUF)                                                        \
  {                                                                           \
    const char* kb = (const char*)lK + (KBUF) * 16384;                        \
    char* pw = (char*)lP + (KBUF) * 8192;                                     \
    RB[0] = fzero; RB[1] = fzero; RB[2] = fzero; RB[3] = fzero;               \
    int trow = tq * 16 + l15;                                                 \
    int swz = (trow & 7) << 4;                                                \
    __builtin_amdgcn_s_setprio(1);                                            \
    _Pragma("unroll")                                                         \
    for (int ec = 0; ec < 4; ++ec) {                                          \
      bf16x8 kf = *(const bf16x8*)(kb + trow * 256 + ((ec * 64 + l4 * 16) ^ swz)); \
      _Pragma("unroll")                                                       \
      for (int qs = 0; qs < 4; ++qs)                                          \
        RB[qs] = __builtin_amdgcn_mfma_f32_16x16x32_bf16(kf, QF(qs, ec), RB[qs], 0, 0, 0); \
    }                                                                         \
    __builtin_amdgcn_s_setprio(0);                                            \
    int tb2 = tq * 32 + l4 * 8;                                               \
    _Pragma("unroll")                                                         \
    for (int qs = 0; qs < 4; ++qs) {                                          \
      float p0 = __builtin_amdgcn_exp2f(RB[qs][0]);                           \
      float p1 = __builtin_amdgcn_exp2f(RB[qs][1]);                           \
      float p2 = __builtin_amdgcn_exp2f(RB[qs][2]);                           \
      float p3 = __builtin_amdgcn_exp2f(RB[qs][3]);                           \
      lsum[qs] += (p0 + p1) + (p2 + p3);                                      \
      uint2 dd;                                                               \
      dd.x = (unsigned)f2bf_tr(p0) | ((unsigned)f2bf_tr(p1) << 16);           \
      dd.y = (unsigned)f2bf_tr(p2) | ((unsigned)f2bf_tr(p3) << 16);           \
      int q = qs * 16 + l15;                                                  \
      *(uint2*)(pw + q * 128 + (tb2 ^ ((q & 7) << 4))) = dd;                  \
    }                                                                         \
  }

#define PV_VISSUE(OFF, TI)                                                    \
  _Pragma("unroll")                                                           \
  for (int kk = 0; kk < 2; ++kk)                                              \
    _Pragma("unroll")                                                         \
    for (int ct = 0; ct < 4; ++ct)                                            \
      RA[(OFF) + kk * 4 + ct] = s2f8(*(const s16x8*)(                         \
          Vb + (size_t)(cq * 64 + ct * 16 + l15) * S_DIM + (TI) * 64 + kk * 32 + l4 * 8));

#define PV_KCOMMIT(OFF, KBUFW)                                                \
  {                                                                           \
    char* kw = (char*)lK + (KBUFW) * 16384;                                   \
    _Pragma("unroll")                                                         \
    for (int jj = 0; jj < 4; ++jj) {                                          \
      int r = kr + 16 * jj;                                                   \
      *(s16x8*)(kw + r * 256 + ((kc * 16) ^ ((r & 7) << 4))) = f2s8(RB[(OFF) + jj]); \
    }                                                                         \
  }

#define PV_KLOAD(OFF, TI)                                                     \
  _Pragma("unroll")                                                           \
  for (int jj = 0; jj < 4; ++jj)                                              \
    RB[(OFF) + jj] = s2f8(*(const s16x8*)(                                    \
        Kb + (size_t)((TI) * 64 + kr + 16 * jj) * E_DIM + kc * 8));

#define PV_MFMA(OFF, PBUF)                                                    \
  {                                                                           \
    const char* pr = (const char*)lP + (PBUF) * 8192;                         \
    _Pragma("unroll")                                                         \
    for (int kk = 0; kk < 2; ++kk) {                                          \
      bf16x8 pf[4];                                                           \
      _Pragma("unroll")                                                       \
      for (int qs = 0; qs < 4; ++qs) {                                        \
        int q = qs * 16 + l15;                                                \
        pf[qs] = *(const bf16x8*)(pr + q * 128 + ((kk * 64 + l4 * 16) ^ ((q & 7) << 4))); \
      }                                                                       \
      __builtin_amdgcn_s_setprio(1);                                          \
      _Pragma("unroll")                                                       \
      for (int ct = 0; ct < 4; ++ct) {                                        \
        bf16x8 vf = as_bf(f2s8(RA[(OFF) + kk * 4 + ct]));                     \
        _Pragma("unroll")                                                     \
        for (int qs = 0; qs < 4; ++qs)                                        \
          acc[qs][ct] = __builtin_amdgcn_mfma_f32_16x16x32_bf16(pf[qs], vf, acc[qs][ct], 0, 0, 0); \
      }                                                                       \
      __builtin_amdgcn_s_setprio(0);                                          \
    }                                                                         \
  }

#define RAW_BARRIER()                                                         \
  asm volatile("s_waitcnt lgkmcnt(0)" ::: "memory");                          \
  __builtin_amdgcn_s_barrier();

__global__ __launch_bounds__(512, 2) void attn_kernel(
    const short* __restrict__ Qg, const short* __restrict__ Kg,
    const short* __restrict__ Xb, short* __restrict__ Yg) {
  __shared__ short lK[2 * 64 * E_DIM];   // 32 KB, dbuf, swizzled [t][e]
  __shared__ short lP[2 * 64 * 64];      // 16 KB, dbuf, swizzled [q][t]
  __shared__ float lsred[4 * 64];        // 1 KB

  int bid = blockIdx.x;
  int xcd = bid & 7;            // dispatch round-robins XCDs
  int n   = xcd >> 1;           // batch pinned to an XCD pair
  int s0  = (((xcd & 1) << 5) + (bid >> 3)) * 64;

  int tid = threadIdx.x;
  int wid = tid >> 6, lane = tid & 63;
  int l15 = lane & 15, l4 = lane >> 4;

  const short* Kb = Kg + (size_t)n * S_DIM * E_DIM;
  const short* Vb = Xb + (size_t)n * (size_t)C_DIM * S_DIM;

  const f32x4 fzero = {0.f, 0.f, 0.f, 0.f};

  // ------------- role-unioned register file (static indices only) -------
  f32x4 RA[16];             // QKT: qf | PV: vpreE(0..7)/vpreO(8..15)
  f32x4 RB[8];              // QKT: sc(0..3) | PV: kpreE(0..3)/kpreO(4..7)
  float lsum[4];            // QKT only
  f32x4 acc[4][4];          // PV only (AGPR)

  int tq = wid;             // QKT: t-quarter
  int cq = wid - 4;         // PV:  c-quarter
  int idx = tid & 255;
  int kr = idx >> 4, kc = idx & 15;   // K staging (PV waves, 256 threads)

  if (wid < 4) {
    #pragma unroll
    for (int qs = 0; qs < 4; ++qs) {
      const short* qp = Qg + ((size_t)n * S_DIM + s0 + qs * 16 + l15) * E_DIM + l4 * 8;
      #pragma unroll
      for (int ec = 0; ec < 4; ++ec) RA[qs * 4 + ec] = b2f8(*(const bf16x8*)(qp + ec * 32));
    }
    #pragma unroll
    for (int j = 0; j < 4; ++j) lsum[j] = 0.f;
  } else {
    #pragma unroll
    for (int a = 0; a < 4; ++a)
      #pragma unroll
      for (int b = 0; b < 4; ++b) acc[a][b] = fzero;
    // stage K tile 0 into lK buf0 (via RB[0..3], dead after commit)
    PV_KLOAD(0, 0);
    PV_KCOMMIT(0, 0);
    // prefetch K tile 1 -> kpreO(RB[4..7]); V tile 0 -> vpreE(RA[0..7])
    PV_KLOAD(4, 1);
    PV_VISSUE(0, 0);
  }
  RAW_BARRIER();

  // ------------- main: 32 iterations x 2 windows, static buffers -----------
  for (int j = 0; j < 32; ++j) {
    int i0 = 2 * j;
    // ---- window i0 (even): QKT on lK buf0 -> lP buf0
    if (wid < 4) {
      QKT_BODY(0);
    } else {
      if (j > 0)  PV_VISSUE(0, i0);            // vpreE <- V tile i0 (cons. i0+1)
      PV_KCOMMIT(4, 1);                         // kpreO -> K buf1 (tile i0+1)
      if (j > 0)  PV_MFMA(8, 1);                // PV tile i0-1 (vpreO, P buf1)
      if (j < 31) PV_KLOAD(0, i0 + 2);          // kpreE <- K tile i0+2
    }
    RAW_BARRIER();
    // ---- window i0+1 (odd): QKT on lK buf1 -> lP buf1
    if (wid < 4) {
      QKT_BODY(1);
    } else {
      PV_VISSUE(8, i0 + 1);                     // vpreO <- V tile i0+1 (cons. i0+2)
      if (j < 31) PV_KCOMMIT(0, 0);             // kpreE -> K buf0 (tile i0+2)
      PV_MFMA(0, 0);                            // PV tile i0 (vpreE, P buf0)
      if (j < 31) PV_KLOAD(4, i0 + 3);          // kpreO <- K tile i0+3
    }
    RAW_BARRIER();
  }
  // final window 64: PV on tile 63 (P in buf1, V in vpreO)
  if (wid >= 4) {
    PV_MFMA(8, 1);
  }

  // ---------------- epilogue ----------------
  if (wid < 4) {
    #pragma unroll
    for (int qs = 0; qs < 4; ++qs) {
      float v = lsum[qs];
      v += __shfl_xor(v, 16);
      v += __shfl_xor(v, 32);
      if (lane < 16) lsred[tq * 64 + qs * 16 + l15] = v;
    }
  }
  __syncthreads();

  short* yst = lK;   // reuse 32 KB as [64 q][256 c] bf16, swizzled
  if (wid >= 4) {
    #pragma unroll
    for (int qs = 0; qs < 4; ++qs) {
      #pragma unroll
      for (int r = 0; r < 4; ++r) {
        int q = qs * 16 + l4 * 4 + r;
        float tot = lsred[q] + lsred[64 + q] + lsred[128 + q] + lsred[192 + q];
        float rl = 1.0f / tot;
        #pragma unroll
        for (int ct = 0; ct < 4; ++ct) {
          int c = cq * 64 + ct * 16 + l15;
          *(unsigned short*)((char*)yst + q * 512 + ((c * 2) ^ ((q & 7) << 4))) =
              f2bf_tr(acc[qs][ct][r] * rl);
        }
      }
    }
  }
  __syncthreads();

  int rr = tid >> 3, chb = tid & 7;
  #pragma unroll
  for (int it = 0; it < 4; ++it) {
    int ch = chb + 8 * it;
    s16x8 v = *(const s16x8*)((char*)yst + rr * 512 + ((ch * 16) ^ ((rr & 7) << 4)));
    *(s16x8*)(Yg + ((size_t)n * S_DIM + s0 + rr) * C_DIM + ch * 8) = v;
  }
}

// ---------------------------------------------------------------------------
// Kernel 3 (MFMA, zero LDS): out[o,s] = x[o,s] + sum_c Wp[o,c] y[s,c]
// ---------------------------------------------------------------------------
__global__ __launch_bounds__(256) void proj_kernel(
    const short* __restrict__ Yg, const short* __restrict__ Wpb,
    const float* __restrict__ x, float* __restrict__ out) {
  int bid = blockIdx.x;
  int n = bid >> 7, s0 = (bid & 127) * 32;
  int tid = threadIdx.x;
  int wid = tid >> 6, lane = tid & 63, l15 = lane & 15, l4 = lane >> 4;

  const f32x4 fzero = {0.f, 0.f, 0.f, 0.f};
  f32x4 acc[2][4];
  #pragma unroll
  for (int a = 0; a < 2; ++a)
    #pragma unroll
    for (int b = 0; b < 4; ++b) acc[a][b] = fzero;

  const short* ybase = Yg + (size_t)n * S_DIM * C_DIM;

  #pragma unroll 2
  for (int kk = 0; kk < 8; ++kk) {
    bf16x8 af[2];
    #pragma unroll
    for (int mf = 0; mf < 2; ++mf)
      af[mf] = *(const bf16x8*)(ybase + (size_t)(s0 + mf * 16 + l15) * C_DIM +
                                kk * 32 + l4 * 8);
    #pragma unroll
    for (int nf = 0; nf < 4; ++nf) {
      int o = wid * 64 + nf * 16 + l15;
      bf16x8 bfr = *(const bf16x8*)(Wpb + o * C_DIM + kk * 32 + l4 * 8);
      #pragma unroll
      for (int mf = 0; mf < 2; ++mf)
        acc[mf][nf] = __builtin_amdgcn_mfma_f32_16x16x32_bf16(af[mf], bfr, acc[mf][nf], 0, 0, 0);
    }
  }

  #pragma unroll
  for (int mf = 0; mf < 2; ++mf) {
    #pragma unroll
    for (int nf = 0; nf < 4; ++nf) {
      int o = wid * 64 + nf * 16 + l15;
      size_t idx = ((size_t)n * C_DIM + o) * (size_t)S_DIM + s0 + mf * 16 + l4 * 4;
      float4 xv = *(const float4*)(x + idx);
      float4 r;
      r.x = xv.x + acc[mf][nf][0];
      r.y = xv.y + acc[mf][nf][1];
      r.z = xv.z + acc[mf][nf][2];
      r.w = xv.w + acc[mf][nf][3];
      *(float4*)(out + idx) = r;
    }
  }
}

// ---------------------------------------------------------------------------
extern "C" void kernel_launch(void* const* d_in, const int* in_sizes, int n_in,
                              void* d_out, int out_size, void* d_ws, size_t ws_size,
                              hipStream_t stream) {
  const float* x   = (const float*)d_in[0];
  const float* Wth = (const float*)d_in[1];
  const float* Wph = (const float*)d_in[2];
  const float* Wpr = (const float*)d_in[3];
  float* out = (float*)d_out;

  short* q_ws  = (short*)d_ws;                              // 4 MB  [N,S,E]
  short* k_ws  = q_ws  + (size_t)4 * S_DIM * E_DIM;         // 4 MB  [N,S,E]
  short* xb_ws = k_ws  + (size_t)4 * S_DIM * E_DIM;         // 8 MB  [N,C,S]
  short* y_ws  = xb_ws + (size_t)4 * C_DIM * S_DIM;         // 8 MB  [N,S,C]
  short* wb_ws = y_ws  + (size_t)4 * S_DIM * C_DIM;         // 256 KB bf16 weights

  float qscale = 1.4426950408889634f / sqrtf(128.0f);       // log2(e)/sqrt(E)

  cast_w_kernel<<<128, 256, 0, stream>>>(Wth, Wph, Wpr, wb_ws);
  mix_kernel<<<512, 256, 0, stream>>>(x, wb_ws, q_ws, k_ws, xb_ws, qscale);
  attn_kernel<<<256, 512, 0, stream>>>(q_ws, k_ws, xb_ws, y_ws);
  proj_kernel<<<512, 256, 0, stream>>>(y_ws, wb_ws + 65536, x, out);
}